// Round 2
// baseline (805.634 us; speedup 1.0000x reference)
//
#include <hip/hip_runtime.h>
#include <hip/hip_cooperative_groups.h>
#include <math.h>

namespace cg = cooperative_groups;

// Persistent cooperative kernel: one launch, 128 WGs x 1024 threads, all
// co-resident (guaranteed by hipLaunchCooperativeKernel). Recurrent weights
// (2 rows/wave) live in persistent VGPRs. Grid-wide deps use
// cg::this_grid().sync() (31 syncs). Internal compute fp32, identical per-dot
// accumulation order to the 500us multi-kernel version.

#define NB 128
#define NT 1024
#define NWAVE (NB * 16)  // 2048 waves

__device__ __forceinline__ float sigf(float x) { return 1.0f / (1.0f + expf(-x)); }

__device__ __forceinline__ float wave_red(float v) {
#pragma unroll
    for (int s = 32; s; s >>= 1) v += __shfl_down(v, s, 64);
    return v;
}

// order-preserving float->uint encoding for atomicMax (inputs have no NaNs)
__device__ __forceinline__ unsigned encf(float f) {
    unsigned u = __float_as_uint(f);
    return (u & 0x80000000u) ? ~u : (u | 0x80000000u);
}
__device__ __forceinline__ float decf(unsigned e) {
    return (e & 0x80000000u) ? __uint_as_float(e ^ 0x80000000u) : __uint_as_float(~e);
}

__device__ __forceinline__ float dotf(const float* __restrict__ w,
                                      const float* __restrict__ x, int lane) {
    float acc = 0.f;
#pragma unroll
    for (int j = 0; j < 4; ++j) {
        float4 a = *reinterpret_cast<const float4*>(w + j * 256 + lane * 4);
        float4 b = *reinterpret_cast<const float4*>(x + j * 256 + lane * 4);
        acc += a.x * b.x + a.y * b.y + a.z * b.z + a.w * b.w;
    }
    return acc;
}

// two weight rows (global) vs one x, x loaded once
__device__ __forceinline__ void dot2_acc(const float* w0, const float* w1,
                                         const float* x, int lane, float& a0, float& a1) {
#pragma unroll
    for (int k = 0; k < 4; ++k) {
        float4 xv = *reinterpret_cast<const float4*>(x + k * 256 + lane * 4);
        float4 u = *reinterpret_cast<const float4*>(w0 + k * 256 + lane * 4);
        float4 v = *reinterpret_cast<const float4*>(w1 + k * 256 + lane * 4);
        a0 += u.x * xv.x + u.y * xv.y + u.z * xv.z + u.w * xv.w;
        a1 += v.x * xv.x + v.y * xv.y + v.z * xv.z + v.w * xv.w;
    }
}

// two register-resident weight rows vs one x
__device__ __forceinline__ void dot2_reg(const float* __restrict__ x, int lane,
                                         const float* wr0, const float* wr1,
                                         float& a0, float& a1) {
#pragma unroll
    for (int k = 0; k < 4; ++k) {
        float4 xv = *reinterpret_cast<const float4*>(x + k * 256 + lane * 4);
        a0 += wr0[4 * k] * xv.x + wr0[4 * k + 1] * xv.y +
              wr0[4 * k + 2] * xv.z + wr0[4 * k + 3] * xv.w;
        a1 += wr1[4 * k] * xv.x + wr1[4 * k + 1] * xv.y +
              wr1[4 * k + 2] * xv.z + wr1[4 * k + 3] * xv.w;
    }
}

// zero the colmax atomic accumulators (runs before mega_k every replay)
__global__ void init_k(unsigned* u) { u[512 + blockIdx.x * 256 + threadIdx.x] = 0; }

__global__ void __launch_bounds__(NT, 4) mega_k(
    const float* __restrict__ tsn, const float* __restrict__ W_fe,
    const float* __restrict__ b_fe, const float* __restrict__ gW_ih0,
    const float* __restrict__ gW_ihR, const float* __restrict__ gb_ih,
    const float* __restrict__ gb_hh, const float* __restrict__ rW_ih,
    const float* __restrict__ rW_hh, const float* __restrict__ rb_ih,
    const float* __restrict__ rb_hh, const float* __restrict__ Wp,
    const float* __restrict__ bp, const float* __restrict__ We2a,
    const float* __restrict__ be2a, const float* __restrict__ We2v,
    const float* __restrict__ be2v, const float* __restrict__ We2n,
    const float* __restrict__ be2n, float* out, float* ws) {

    cg::grid_group grid = cg::this_grid();

    unsigned* maxenc = (unsigned*)ws + 512;   // 1024 encoded col maxes
    float* fs   = ws + 2048;
    float* hgA  = ws + 3072;
    float* hgB  = ws + 4096;
    float* sv   = ws + 5120;
    float* a2in = ws + 6144;
    float* f2in = ws + 7168;
    float* pa   = ws + 8192;    // 2*1024
    float* ajs1 = ws + 10240;   // 10*1024
    float* nfs1 = ws + 20480;
    float* ajs2 = ws + 30720;
    float* nfs2 = ws + 40960;   // ends at 51200 floats (~200 KiB)

    __shared__ float gg[32];
    __shared__ float cc_l[8];
    __shared__ float sh_d[12];
    __shared__ float sh_s1[10];
    __shared__ float sh_bd1;
    __shared__ int sh_istar;
    __shared__ int sh_sel[2];

    const int tid = threadIdx.x, b = blockIdx.x;
    const int w = tid >> 6, lane = tid & 63;
    const int g4 = w >> 2, jr = w & 3;            // wave covers (gate g4, jj=jr / jr+4)
    const int ridx0 = g4 * 8 + jr, ridx1 = ridx0 + 4;
    const int row0 = (g4 << 10) + 8 * b + jr;     // global gate-matrix row
    const int row1 = row0 + 4;
    const int gw = b * 16 + w;                    // global wave id, 0..2047

    // ---- A: recurrent weight rows -> persistent registers + colmax(tsn) ----
    float wr0[16], wr1[16];
    {
        const float* s0 = rW_hh + (size_t)row0 * 1024;
        const float* s1 = rW_hh + (size_t)row1 * 1024;
#pragma unroll
        for (int k = 0; k < 4; ++k) {
            float4 a = *reinterpret_cast<const float4*>(s0 + k * 256 + lane * 4);
            float4 c = *reinterpret_cast<const float4*>(s1 + k * 256 + lane * 4);
            wr0[4 * k] = a.x; wr0[4 * k + 1] = a.y; wr0[4 * k + 2] = a.z; wr0[4 * k + 3] = a.w;
            wr1[4 * k] = c.x; wr1[4 * k + 1] = c.y; wr1[4 * k + 2] = c.z; wr1[4 * k + 3] = c.w;
        }
        float m = -INFINITY;
        const float* tcol = tsn + (size_t)(32 * b) * 1024 + tid;  // 32 rows/WG, col=tid
#pragma unroll 4
        for (int r = 0; r < 32; ++r) m = fmaxf(m, tcol[(size_t)r * 1024]);
        atomicMax(&maxenc[tid], encf(m));
    }
    grid.sync();

    // ---- C: fs = W_fe @ maxv + b_fe ----
    if (gw < 1024) {
        const float* wr = W_fe + (size_t)gw * 1024;
        float acc = 0.f;
#pragma unroll
        for (int k = 0; k < 4; ++k) {
            float4 a = *reinterpret_cast<const float4*>(wr + k * 256 + lane * 4);
            uint4 e = *reinterpret_cast<const uint4*>(maxenc + k * 256 + lane * 4);
            acc += a.x * decf(e.x) + a.y * decf(e.y) + a.z * decf(e.z) + a.w * decf(e.w);
        }
        acc = wave_red(acc);
        if (lane == 0) fs[gw] = acc + b_fe[gw];
    }
    grid.sync();

    // ---- D: 5-layer goal LSTM (zero states: c = sig(i)*tanh(g), f unused) ----
    {
        const float* xin = fs;
        float* hout = hgA;
#pragma unroll 1
        for (int L = 0; L < 5; ++L) {
            const float *w0p, *w1p;
            if (L == 0) {
                w0p = gW_ih0 + (size_t)row0 * 2048;  // cols 0:1024 (x = concat(fs, 0))
                w1p = gW_ih0 + (size_t)row1 * 2048;
            } else {
                const float* base = gW_ihR + (size_t)(L - 1) * 4096 * 1024;
                w0p = base + (size_t)row0 * 1024;
                w1p = base + (size_t)row1 * 1024;
            }
            float a0 = 0.f, a1 = 0.f;
            dot2_acc(w0p, w1p, xin, lane, a0, a1);
            a0 = wave_red(a0);
            a1 = wave_red(a1);
            if (lane == 0) {
                gg[ridx0] = a0 + gb_ih[L * 4096 + row0] + gb_hh[L * 4096 + row0];
                gg[ridx1] = a1 + gb_ih[L * 4096 + row1] + gb_hh[L * 4096 + row1];
            }
            __syncthreads();
            if (tid < 8) {
                float gi = gg[tid], gc = gg[16 + tid], go = gg[24 + tid];
                float c = sigf(gi) * tanhf(gc);
                hout[8 * b + tid] = sigf(go) * tanhf(c);
            }
            grid.sync();
            xin = hout;
            hout = (hout == hgA) ? hgB : hgA;
        }
    }
    const float* gv = hgA;  // goal state g

    // ---- E: exp-1 fixed gates (regs) + cell0 + sv1 + cur_action on idle waves ----
    float gxr0, gxr1;  // fixed-input gate preactivation (valid in lane 0)
    {
        float a0 = 0.f, a1 = 0.f;
        dot2_acc(rW_ih + (size_t)row0 * 2048 + 1024, rW_ih + (size_t)row1 * 2048 + 1024,
                 fs, lane, a0, a1);
        gxr0 = wave_red(a0);
        gxr1 = wave_red(a1);
        if (lane == 0) {
            gxr0 += rb_ih[row0] + rb_hh[row0];
            gxr1 += rb_ih[row1] + rb_hh[row1];
            gg[ridx0] = gxr0;
            gg[ridx1] = gxr1;
        }
        __syncthreads();
        if (tid < 8) {
            float gi = gg[tid], gc = gg[16 + tid], go = gg[24 + tid];
            float c = sigf(gi) * tanhf(gc);
            cc_l[tid] = c;
            ajs1[8 * b + tid] = sigf(go) * tanhf(c);
        }
        for (int task = gw; task < 1024 + 2513; task += NWAVE) {
            if (task < 1024) {  // sv1[i] = Wp[:,0:1024]@fs + Wp[:,2048:]@g + bp
                float acc = dotf(Wp + (size_t)task * 3072, fs, lane) +
                            dotf(Wp + (size_t)task * 3072 + 2048, gv, lane);
                acc = wave_red(acc);
                if (lane == 0) sv[task] = acc + bp[task];
            } else {  // cur_action
                int r = task - 1024;
                float acc = dotf(We2a + (size_t)r * 1024, fs, lane);
                acc = wave_red(acc);
                if (lane == 0) out[11100 + r] = acc + be2a[r];
            }
        }
    }
    grid.sync();

    // ---- F: exp-1 recurrence t=1..9, weights in registers, c in LDS ----
#pragma unroll 1
    for (int t = 1; t < 10; ++t) {
        const float* hp = ajs1 + (t - 1) * 1024;
        float a0 = 0.f, a1 = 0.f;
        dot2_reg(hp, lane, wr0, wr1, a0, a1);
        a0 = wave_red(a0);
        a1 = wave_red(a1);
        if (lane == 0) { gg[ridx0] = a0 + gxr0; gg[ridx1] = a1 + gxr1; }
        __syncthreads();
        if (tid < 8) {
            float gi = gg[tid], gf = gg[8 + tid], gc = gg[16 + tid], go = gg[24 + tid];
            float c = sigf(gf) * cc_l[tid] + sigf(gi) * tanhf(gc);
            cc_l[tid] = c;
            ajs1[t * 1024 + 8 * b + tid] = sigf(go) * tanhf(c);
        }
        grid.sync();
    }

    // ---- G: nfs1 (wave = (row i, 5 timesteps); weight row reused) ----
    {
        const int i = gw >> 1;
        const int t0 = (gw & 1) * 5;
        const float* wr = Wp + (size_t)i * 3072 + 1024;
        float wf[16];
#pragma unroll
        for (int k = 0; k < 4; ++k) {
            float4 a = *reinterpret_cast<const float4*>(wr + k * 256 + lane * 4);
            wf[4 * k] = a.x; wf[4 * k + 1] = a.y; wf[4 * k + 2] = a.z; wf[4 * k + 3] = a.w;
        }
#pragma unroll
        for (int tt = 0; tt < 5; ++tt) {
            const float* av = ajs1 + (t0 + tt) * 1024;
            float acc = 0.f;
#pragma unroll
            for (int k = 0; k < 4; ++k) {
                float4 v = *reinterpret_cast<const float4*>(av + k * 256 + lane * 4);
                acc += wf[4 * k] * v.x + wf[4 * k + 1] * v.y + wf[4 * k + 2] * v.z +
                       wf[4 * k + 3] * v.w;
            }
            acc = wave_red(acc);
            if (lane == 0) nfs1[(t0 + tt) * 1024 + i] = fmaxf(sv[i] + acc, 0.f);
        }
    }
    grid.sync();

    // ---- H: scores1 + argmin + extract a2in/f2in (WG 0) ----
    if (b == 0) {
        if (w < 11) {
            const float* vv = (w < 10) ? (nfs1 + w * 1024) : fs;  // w==10 -> bd0
            float p = 0.f;
#pragma unroll
            for (int k = 0; k < 4; ++k) {
                float4 v = *reinterpret_cast<const float4*>(vv + k * 256 + lane * 4);
                float4 gq = *reinterpret_cast<const float4*>(gv + k * 256 + lane * 4);
                float dx = v.x - gq.x, dy = v.y - gq.y, dz = v.z - gq.z, dw = v.w - gq.w;
                p += dx * dx + dy * dy + dz * dz + dw * dw;
            }
            p = wave_red(p);
            if (lane == 0) sh_d[w] = p * (1.0f / 1024.0f);
        }
        __syncthreads();
        if (tid == 0) {
            float bd = sh_d[10];
            float smin = INFINITY;
            int im = 0;
            for (int t = 0; t < 10; ++t) {
                float s = bd - sh_d[t];
                sh_s1[t] = s;
                if (s < smin) { smin = s; im = t; }
                if (sh_d[t] < bd) bd = sh_d[t];
            }
            sh_bd1 = bd;
            sh_istar = im;
        }
        __syncthreads();
        {
            int im = sh_istar;
            float a = ajs1[im * 1024 + tid];
            float f = nfs1[im * 1024 + tid];
            a2in[tid] = a;
            f2in[tid] = f;
            out[10076 + tid] = f;
        }
    }
    grid.sync();

    // ---- I: exp-2 fixed gates + cell0 + sv2 ----
    {
        float a0 = 0.f, a1 = 0.f;
        dot2_acc(rW_ih + (size_t)row0 * 2048, rW_ih + (size_t)row1 * 2048, a2in, lane, a0, a1);
        dot2_acc(rW_ih + (size_t)row0 * 2048 + 1024, rW_ih + (size_t)row1 * 2048 + 1024,
                 f2in, lane, a0, a1);
        gxr0 = wave_red(a0);
        gxr1 = wave_red(a1);
        if (lane == 0) {
            gxr0 += rb_ih[row0] + rb_hh[row0];
            gxr1 += rb_ih[row1] + rb_hh[row1];
            gg[ridx0] = gxr0;
            gg[ridx1] = gxr1;
        }
        __syncthreads();
        if (tid < 8) {
            float gi = gg[tid], gc = gg[16 + tid], go = gg[24 + tid];
            float c = sigf(gi) * tanhf(gc);
            cc_l[tid] = c;
            ajs2[8 * b + tid] = sigf(go) * tanhf(c);
        }
        if (gw < 1024) {
            float acc = dotf(Wp + (size_t)gw * 3072, f2in, lane) +
                        dotf(Wp + (size_t)gw * 3072 + 2048, gv, lane);
            acc = wave_red(acc);
            if (lane == 0) sv[gw] = acc + bp[gw];
        }
    }
    grid.sync();

    // ---- F': exp-2 recurrence t=1..9 ----
#pragma unroll 1
    for (int t = 1; t < 10; ++t) {
        const float* hp = ajs2 + (t - 1) * 1024;
        float a0 = 0.f, a1 = 0.f;
        dot2_reg(hp, lane, wr0, wr1, a0, a1);
        a0 = wave_red(a0);
        a1 = wave_red(a1);
        if (lane == 0) { gg[ridx0] = a0 + gxr0; gg[ridx1] = a1 + gxr1; }
        __syncthreads();
        if (tid < 8) {
            float gi = gg[tid], gf = gg[8 + tid], gc = gg[16 + tid], go = gg[24 + tid];
            float c = sigf(gf) * cc_l[tid] + sigf(gi) * tanhf(gc);
            cc_l[tid] = c;
            ajs2[t * 1024 + 8 * b + tid] = sigf(go) * tanhf(c);
        }
        grid.sync();
    }

    // ---- J: nfs2 ----
    {
        const int i = gw >> 1;
        const int t0 = (gw & 1) * 5;
        const float* wr = Wp + (size_t)i * 3072 + 1024;
        float wf[16];
#pragma unroll
        for (int k = 0; k < 4; ++k) {
            float4 a = *reinterpret_cast<const float4*>(wr + k * 256 + lane * 4);
            wf[4 * k] = a.x; wf[4 * k + 1] = a.y; wf[4 * k + 2] = a.z; wf[4 * k + 3] = a.w;
        }
#pragma unroll
        for (int tt = 0; tt < 5; ++tt) {
            const float* av = ajs2 + (t0 + tt) * 1024;
            float acc = 0.f;
#pragma unroll
            for (int k = 0; k < 4; ++k) {
                float4 v = *reinterpret_cast<const float4*>(av + k * 256 + lane * 4);
                acc += wf[4 * k] * v.x + wf[4 * k + 1] * v.y + wf[4 * k + 2] * v.z +
                       wf[4 * k + 3] * v.w;
            }
            acc = wave_red(acc);
            if (lane == 0) nfs2[(t0 + tt) * 1024 + i] = fmaxf(sv[i] + acc, 0.f);
        }
    }
    grid.sync();

    // ---- K: scores2 + top-2 + pa/pfeat/pgoal (WG 0) ----
    if (b == 0) {
        if (w < 10) {
            const float* vv = nfs2 + w * 1024;
            float p = 0.f;
#pragma unroll
            for (int k = 0; k < 4; ++k) {
                float4 v = *reinterpret_cast<const float4*>(vv + k * 256 + lane * 4);
                float4 gq = *reinterpret_cast<const float4*>(gv + k * 256 + lane * 4);
                float dx = v.x - gq.x, dy = v.y - gq.y, dz = v.z - gq.z, dw = v.w - gq.w;
                p += dx * dx + dy * dy + dz * dz + dw * dw;
            }
            p = wave_red(p);
            if (lane == 0) sh_d[w] = p * (1.0f / 1024.0f);
        }
        __syncthreads();
        if (tid == 0) {
            float sc[20];
            int im = sh_istar;
            for (int t = 0; t < 10; ++t) sc[t] = (t == im) ? INFINITY : sh_s1[t];
            float bd = sh_bd1;
            for (int t = 0; t < 10; ++t) {
                float s = bd - sh_d[t];
                sc[10 + t] = s;
                if (sh_d[t] < bd) bd = sh_d[t];
            }
            int i0 = 0; float m0 = INFINITY;
            for (int t = 0; t < 20; ++t) if (sc[t] < m0) { m0 = sc[t]; i0 = t; }
            int i1 = 0; float m1 = INFINITY;
            for (int t = 0; t < 20; ++t) { if (t == i0) continue; if (sc[t] < m1) { m1 = sc[t]; i1 = t; } }
            sh_sel[0] = i0; sh_sel[1] = i1;
        }
        __syncthreads();
#pragma unroll
        for (int p = 0; p < 2; ++p) {
            int idx = sh_sel[p];
            float av, fv;
            if (idx < 10) {
                av = ajs1[idx * 1024 + tid] * 0.5f;
                fv = (fs[tid] + nfs1[idx * 1024 + tid]) * 0.5f;
            } else {
                int t2 = idx - 10;
                av = (a2in[tid] + ajs2[t2 * 1024 + tid]) * (1.0f / 3.0f);
                fv = (fs[tid] + f2in[tid] + nfs2[t2 * 1024 + tid]) * (1.0f / 3.0f);
            }
            pa[p * 1024 + tid] = av;
            out[5980 + p * 1024 + tid] = fv;       // pfeat
            out[8028 + p * 1024 + tid] = gv[tid];  // pgoal
        }
    }
    grid.sync();

    // ---- L: heads (5980 dot-1024 tasks over 2048 waves) ----
    for (int task = gw; task < 5980; task += NWAVE) {
        int p = (task < 2990) ? 0 : 1;
        int r = task - p * 2990;
        const float* W; const float* bb; int rr, outoff;
        if (r < 2513)      { W = We2a; bb = be2a; rr = r;        outoff = p * 2513 + rr; }
        else if (r < 2638) { W = We2v; bb = be2v; rr = r - 2513; outoff = 5026 + p * 125 + rr; }
        else               { W = We2n; bb = be2n; rr = r - 2638; outoff = 5276 + p * 352 + rr; }
        float acc = dotf(W + (size_t)rr * 1024, pa + p * 1024, lane);
        acc = wave_red(acc);
        if (lane == 0) out[outoff] = acc + bb[rr];
    }
}

extern "C" void kernel_launch(void* const* d_in, const int* in_sizes, int n_in,
                              void* d_out, int out_size, void* d_ws, size_t ws_size,
                              hipStream_t stream) {
    const float* tsn    = (const float*)d_in[0];
    const float* W_fe   = (const float*)d_in[1];
    const float* b_fe   = (const float*)d_in[2];
    const float* gW_ih0 = (const float*)d_in[3];
    const float* gW_ihR = (const float*)d_in[4];
    // d_in[5] = gW_hh: multiplied by zero hidden state -> never needed
    const float* gb_ih  = (const float*)d_in[6];
    const float* gb_hh  = (const float*)d_in[7];
    const float* rW_ih  = (const float*)d_in[8];
    const float* rW_hh  = (const float*)d_in[9];
    const float* rb_ih  = (const float*)d_in[10];
    const float* rb_hh  = (const float*)d_in[11];
    const float* Wp     = (const float*)d_in[12];
    const float* bp     = (const float*)d_in[13];
    const float* We2a   = (const float*)d_in[14];
    const float* be2a   = (const float*)d_in[15];
    const float* We2v   = (const float*)d_in[16];
    const float* be2v   = (const float*)d_in[17];
    const float* We2n   = (const float*)d_in[18];
    const float* be2n   = (const float*)d_in[19];
    float* out = (float*)d_out;
    float* wsf = (float*)d_ws;

    init_k<<<4, 256, 0, stream>>>((unsigned*)d_ws);  // zero colmax accumulators

    void* args[] = {
        (void*)&tsn,  (void*)&W_fe, (void*)&b_fe,  (void*)&gW_ih0, (void*)&gW_ihR,
        (void*)&gb_ih, (void*)&gb_hh, (void*)&rW_ih, (void*)&rW_hh, (void*)&rb_ih,
        (void*)&rb_hh, (void*)&Wp,   (void*)&bp,    (void*)&We2a,  (void*)&be2a,
        (void*)&We2v, (void*)&be2v,  (void*)&We2n,  (void*)&be2n,  (void*)&out,
        (void*)&wsf
    };
    hipLaunchCooperativeKernel((const void*)mega_k, dim3(NB), dim3(NT), args, 0, stream);
}